// Round 1
// baseline (423.285 us; speedup 1.0000x reference)
//
#include <hip/hip_runtime.h>

// Problem constants (B=4, C=256, H=W=64, heads=4)
#define NPOS   4096          // H*W
#define TOTP   16384         // B*NPOS
#define C      256
#define OC3    768           // 3*C
#define DH     64

typedef unsigned short ushort_t;
typedef __attribute__((ext_vector_type(8))) short short8;   // 8 bf16 (4 VGPRs) MFMA A/B frag
typedef __attribute__((ext_vector_type(4))) float f32x4;    // MFMA C/D frag

__device__ __forceinline__ f32x4 mfma16(short8 a, short8 b, f32x4 c) {
  return __builtin_amdgcn_mfma_f32_16x16x32_bf16(a, b, c, 0, 0, 0);
}

// fp32 -> bf16 bits, round-to-nearest-even (inputs finite)
__device__ __forceinline__ ushort_t f2bf(float f) {
  union { float f; unsigned int u; } v;
  v.f = f;
  unsigned int r = v.u + 0x7FFFu + ((v.u >> 16) & 1u);
  return (ushort_t)(r >> 16);
}

// ---------------------------------------------------------------------------
// Pack weights to bf16. Q rows (o<256) of w_qkv get the 1/8 attention scale
// folded in (exact in bf16: exponent shift).
// grid 256 x 256 threads, each thread packs 4 floats.
__global__ __launch_bounds__(256) void pack_w(const float* __restrict__ wq,
                                              const float* __restrict__ wp,
                                              ushort_t* __restrict__ wqb,
                                              ushort_t* __restrict__ wpb) {
  int idx = blockIdx.x * 256 + threadIdx.x;
  if (idx < 49152) {                       // w_qkv: 768*256 = 196608 = 49152*4
    float4 v = *(const float4*)(wq + (size_t)idx * 4);
    float sc = (idx * 4 < 65536) ? 0.125f : 1.0f;   // rows [0,256) = Q channels
    ushort_t* d = wqb + (size_t)idx * 4;
    unsigned long long pk =
        (unsigned long long)f2bf(v.x * sc) |
        ((unsigned long long)f2bf(v.y * sc) << 16) |
        ((unsigned long long)f2bf(v.z * sc) << 32) |
        ((unsigned long long)f2bf(v.w * sc) << 48);
    *(unsigned long long*)d = pk;
  } else {                                 // w_proj: 256*256 = 65536 = 16384*4
    int j = idx - 49152;
    float4 v = *(const float4*)(wp + (size_t)j * 4);
    ushort_t* d = wpb + (size_t)j * 4;
    unsigned long long pk =
        (unsigned long long)f2bf(v.x) |
        ((unsigned long long)f2bf(v.y) << 16) |
        ((unsigned long long)f2bf(v.z) << 32) |
        ((unsigned long long)f2bf(v.w) << 48);
    *(unsigned long long*)d = pk;
  }
}

// ---------------------------------------------------------------------------
// x [b][c][n] fp32  ->  xT [b*4096+n][c] bf16   (LDS tile transpose)
// grid (64 n-tiles, 4 c-tiles, 4 b), 256 threads
__global__ __launch_bounds__(256) void transpose_pack(const float* __restrict__ x,
                                                      ushort_t* __restrict__ xT) {
  __shared__ ushort_t tile[64][68];
  int nb = blockIdx.x * 64, cb = blockIdx.y * 64, b = blockIdx.z;
  int tr = threadIdx.x >> 4;            // 0..15
  int tc = (threadIdx.x & 15) * 4;      // 0..60
  const float* src = x + ((size_t)b * C + cb) * NPOS + nb;
#pragma unroll
  for (int it = 0; it < 4; ++it) {
    int c = tr + it * 16;
    float4 v = *(const float4*)(src + (size_t)c * NPOS + tc);
    tile[c][tc + 0] = f2bf(v.x);
    tile[c][tc + 1] = f2bf(v.y);
    tile[c][tc + 2] = f2bf(v.z);
    tile[c][tc + 3] = f2bf(v.w);
  }
  __syncthreads();
  ushort_t* dst = xT + ((size_t)b * NPOS + nb) * C + cb;
#pragma unroll
  for (int it = 0; it < 4; ++it) {
    int n = tr + it * 16;
    unsigned long long pk =
        (unsigned long long)tile[tc + 0][n] |
        ((unsigned long long)tile[tc + 1][n] << 16) |
        ((unsigned long long)tile[tc + 2][n] << 32) |
        ((unsigned long long)tile[tc + 3][n] << 48);
    *(unsigned long long*)(dst + (size_t)n * C + tc) = pk;
  }
}

// ---------------------------------------------------------------------------
// QKV GEMM: qkv[p][o] = sum_c xT[p][c] * Wq[o][c]
// Orientation: D rows = positions, cols = o  -> coalesced bf16 stores to [p][768].
// All fragments are direct 16B global loads (no LDS, no barriers).
// grid (256 p-tiles, 12 o-tiles), 4 waves, wave = 16 p x 64 o.
__global__ __launch_bounds__(256) void gemm_qkv(const ushort_t* __restrict__ xT,
                                                const ushort_t* __restrict__ Wq,
                                                ushort_t* __restrict__ qkv) {
  int w = threadIdx.x >> 6, l = threadIdx.x & 63;
  int lr = l & 15, lg = l >> 4;
  int mbase = blockIdx.x * 64 + w * 16;   // position rows
  int nbase = blockIdx.y * 64;            // o cols
  const ushort_t* arow = xT + (size_t)(mbase + lr) * C + lg * 8;
  f32x4 acc[4] = {};
#pragma unroll
  for (int kk = 0; kk < 8; ++kk) {
    short8 a = *(const short8*)(arow + kk * 32);
#pragma unroll
    for (int t = 0; t < 4; ++t) {
      short8 b = *(const short8*)(Wq + (size_t)(nbase + t * 16 + lr) * C + kk * 32 + lg * 8);
      acc[t] = mfma16(a, b, acc[t]);
    }
  }
#pragma unroll
  for (int t = 0; t < 4; ++t)
#pragma unroll
    for (int i = 0; i < 4; ++i)
      qkv[(size_t)(mbase + lg * 4 + i) * OC3 + nbase + t * 16 + lr] = f2bf(acc[t][i]);
}

// ---------------------------------------------------------------------------
// Flash attention. grid (64 q-tiles, 16 b*h), 4 waves; wave = 16 q-rows.
// qkv layout [p][768]: Q at col h*64 (pre-scaled), K at 256+h*64, V at 512+h*64.
// K staged [key][d] (direct b128 frags), V staged transposed [d][key],
// P bounced through per-wave LDS to reach A-fragment layout.
__global__ __launch_bounds__(256) void attn_kernel(const ushort_t* __restrict__ qkv,
                                                   ushort_t* __restrict__ ao) {
  __shared__ ushort_t Ks[64][72];
  __shared__ ushort_t Vs[64][72];        // Vs[d][key]
  __shared__ ushort_t Pw[4][16][72];     // per-wave P [q][key]
  int w = threadIdx.x >> 6, l = threadIdx.x & 63;
  int lr = l & 15, lg = l >> 4;
  int bh = blockIdx.y;
  int b = bh >> 2, h = bh & 3;
  size_t bbase = (size_t)b * NPOS;
  int qbase = blockIdx.x * 64 + w * 16;

  // Q fragments hoisted (scale folded into W_q)
  const ushort_t* qrow = qkv + (bbase + qbase + lr) * OC3 + h * DH + lg * 8;
  short8 aq0 = *(const short8*)(qrow);
  short8 aq1 = *(const short8*)(qrow + 32);

  f32x4 o[4] = {};
  float mi[4] = {-1e30f, -1e30f, -1e30f, -1e30f};
  float li[4] = {0.f, 0.f, 0.f, 0.f};
  int tid = threadIdx.x;

  for (int kt = 0; kt < 64; ++kt) {
    // ---- stage K tile [64][64] and V^T tile [64][64] ----
#pragma unroll
    for (int it = 0; it < 2; ++it) {
      int idx = tid + it * 256;          // 0..511
      int row = idx >> 3, c8 = (idx & 7) * 8;
      const ushort_t* src = qkv + (bbase + (size_t)kt * 64 + row) * OC3 + C + h * DH + c8;
      *(short8*)&Ks[row][c8] = *(const short8*)src;          // K[key][d]
      short8 vv = *(const short8*)(src + C);                 // V[key][d]
#pragma unroll
      for (int j = 0; j < 8; ++j) Vs[c8 + j][row] = (ushort_t)vv[j];
    }
    __syncthreads();

    // ---- S = Q K^T (scale pre-folded) ----
    f32x4 s[4] = {};
#pragma unroll
    for (int t = 0; t < 4; ++t) {
      short8 bk0 = *(const short8*)&Ks[t * 16 + lr][lg * 8];
      short8 bk1 = *(const short8*)&Ks[t * 16 + lr][32 + lg * 8];
      s[t] = mfma16(aq0, bk0, s[t]);
      s[t] = mfma16(aq1, bk1, s[t]);
    }

    // ---- online softmax (rows: q = lg*4+i; 16 lanes of a row group reduce) ----
#pragma unroll
    for (int i = 0; i < 4; ++i) {
      float mx = fmaxf(fmaxf(s[0][i], s[1][i]), fmaxf(s[2][i], s[3][i]));
#pragma unroll
      for (int msk = 1; msk <= 8; msk <<= 1) mx = fmaxf(mx, __shfl_xor(mx, msk, 64));
      float mnew = fmaxf(mi[i], mx);
      float corr = __expf(mi[i] - mnew);
      float rs = 0.f;
#pragma unroll
      for (int t = 0; t < 4; ++t) {
        float p = __expf(s[t][i] - mnew);
        rs += p;
        Pw[w][lg * 4 + i][t * 16 + lr] = f2bf(p);
      }
#pragma unroll
      for (int msk = 1; msk <= 8; msk <<= 1) rs += __shfl_xor(rs, msk, 64);
      li[i] = li[i] * corr + rs;
      mi[i] = mnew;
      o[0][i] *= corr; o[1][i] *= corr; o[2][i] *= corr; o[3][i] *= corr;
    }
    __syncthreads();

    // ---- O += P V ----
#pragma unroll
    for (int kk = 0; kk < 2; ++kk) {
      short8 ap = *(const short8*)&Pw[w][lr][kk * 32 + lg * 8];
#pragma unroll
      for (int t = 0; t < 4; ++t) {
        short8 bv = *(const short8*)&Vs[t * 16 + lr][kk * 32 + lg * 8];
        o[t] = mfma16(ap, bv, o[t]);
      }
    }
    __syncthreads();
  }

  // ---- epilogue: ao[p][h*64+d] = O/li ----
#pragma unroll
  for (int i = 0; i < 4; ++i) {
    float inv = 1.0f / li[i];
    int p = qbase + lg * 4 + i;
#pragma unroll
    for (int t = 0; t < 4; ++t)
      ao[(bbase + p) * C + h * DH + t * 16 + lr] = f2bf(o[t][i] * inv);
  }
}

// ---------------------------------------------------------------------------
// Proj GEMM: out[b][o][n] = sum_c Wp[o][c]*ao[p][c] + bias[o]
// Orientation: D rows = o, cols = positions -> coalesced fp32 stores to [o][n].
// grid (256 p-tiles, 4 o-tiles), 4 waves, wave = 16 o x 64 p.
__global__ __launch_bounds__(256) void gemm_proj(const ushort_t* __restrict__ ao,
                                                 const ushort_t* __restrict__ Wp,
                                                 const float* __restrict__ bias,
                                                 float* __restrict__ out) {
  int w = threadIdx.x >> 6, l = threadIdx.x & 63;
  int lr = l & 15, lg = l >> 4;
  int obase = blockIdx.y * 64 + w * 16;
  int pbase = blockIdx.x * 64;
  const ushort_t* arow = Wp + (size_t)(obase + lr) * C + lg * 8;
  f32x4 acc[4] = {};
#pragma unroll
  for (int kk = 0; kk < 8; ++kk) {
    short8 a = *(const short8*)(arow + kk * 32);
#pragma unroll
    for (int t = 0; t < 4; ++t) {
      short8 b = *(const short8*)(ao + (size_t)(pbase + t * 16 + lr) * C + kk * 32 + lg * 8);
      acc[t] = mfma16(a, b, acc[t]);
    }
  }
#pragma unroll
  for (int i = 0; i < 4; ++i) {
    int oc = obase + lg * 4 + i;
    float bv = bias[oc];
#pragma unroll
    for (int t = 0; t < 4; ++t) {
      int p = pbase + t * 16 + lr;
      out[((size_t)(p >> 12) * C + oc) * NPOS + (p & 4095)] = acc[t][i] + bv;
    }
  }
}

// ---------------------------------------------------------------------------
extern "C" void kernel_launch(void* const* d_in, const int* in_sizes, int n_in,
                              void* d_out, int out_size, void* d_ws, size_t ws_size,
                              hipStream_t stream) {
  const float* x      = (const float*)d_in[0];
  const float* w_qkv  = (const float*)d_in[1];
  const float* w_proj = (const float*)d_in[2];
  const float* b_proj = (const float*)d_in[3];
  float* out = (float*)d_out;

  char* ws = (char*)d_ws;
  ushort_t* xT  = (ushort_t*)(ws);                 // 16384*256*2  = 8,388,608
  ushort_t* wqb = (ushort_t*)(ws + 8388608);       // 768*256*2    =   393,216
  ushort_t* wpb = (ushort_t*)(ws + 8781824);       // 256*256*2    =   131,072
  ushort_t* qkv = (ushort_t*)(ws + 8912896);       // 16384*768*2  = 25,165,824
  ushort_t* ao  = (ushort_t*)(ws + 34078720);      // 16384*256*2  = 8,388,608
                                                   // total 42,467,328 bytes

  pack_w<<<256, 256, 0, stream>>>(w_qkv, w_proj, wqb, wpb);
  transpose_pack<<<dim3(64, 4, 4), 256, 0, stream>>>(x, xT);
  gemm_qkv<<<dim3(256, 12), 256, 0, stream>>>(xT, wqb, qkv);
  attn_kernel<<<dim3(64, 16), 256, 0, stream>>>(qkv, ao);
  gemm_proj<<<dim3(256, 4), 256, 0, stream>>>(ao, wpb, b_proj, out);
}